// Round 10
// baseline (119.815 us; speedup 1.0000x reference)
//
#include <hip/hip_runtime.h>
#include <stdint.h>

// Croston's method: B=8192 series x T=2048 steps. out = Z'/V' per step.
//
// Round 21: break wave lockstep with a cross-series persistent pipeline.
// R19/R20 accounting (per CU): HBM ~16us + DS-pipe ~10.5us + VALU ~7.3us.
// Serialized sum = 34us == measured; overlapped = ~17us. One-series-per-
// wave puts ALL waves in the same phase at the same time (global load
// burst -> global compute -> global store burst): the pipes never overlap.
// R20 (2-stage half pipeline, 32 waves/CU) was neutral -> not TLP-bound,
// coarse 2-stage overlap insufficient; the lockstep itself is the cost.
// Fix: 2048 waves (512 blocks, 2/CU), each owns 4 CONSECUTIVE series:
//   prologue: load S0 (8x 1KB coalesced insts)
//   iter i:  issue S(i+1) loads  -> fly under S(i) transpose+scan
//            transpose-in S(i) (vmcnt waits only on S(i): in-order queue
//            lets S(i-1) stores + S(i+1) loads stay outstanding)
//            fold+scan+replay S(i)
//            transpose-out + store S(i) -> drains under S(i+1) scan
// Each wave's window now mixes vmem+DS+VALU at ~400-cyc grain; waves
// drift out of phase; ramp is paid once per 4 series.
// Per-series scan = R19's verified structure (8KB/wave transpose layout
// verbatim: row=G>>3, quad=(G&7)^((G>>3)&7); all wave64 b128 phases cover
// 8 bank-quads/octet = structural floor) + R20's p==az reduction; the
// half-carry is dropped (series independent: no totals needed).
// LDS 8KB/wave x 4 = 32KB/block, grid 512 = 2 blocks/CU exactly.

#define TLEN 2048

typedef float vf4 __attribute__((ext_vector_type(4)));

__global__ __launch_bounds__(256) void croston_kernel(
    const float* __restrict__ x,
    const float* __restrict__ alpha,
    const float* __restrict__ Z0,
    const float* __restrict__ V0,
    const float* __restrict__ q0,
    float* __restrict__ out)
{
    __shared__ __attribute__((aligned(16))) float lds[4][2048]; // 8KB/wave

    const int warp = threadIdx.x >> 6;
    const int lane = threadIdx.x & 63;
    const int wave = blockIdx.x * 4 + warp;   // 0..2047
    const int wid0 = wave * 4;                // 4 consecutive series
    float* W = lds[warp];                     // wave-private

    const float a  = alpha[0];
    const float ma = 1.0f - a;

    // R19 transpose addressing (verified):
    const int rg   = lane >> 3;                       // row-in-inst
    const int e    = (lane & 7) ^ rg;                 // write-side quad swizzle
    const int goff = rg * 32 + (e << 2);              // + j*256
    const int l7   = lane & 7;                        // read-side key
    const int lbase = lane * 32;

    // Hoist all 4 series' initial states (wave-uniform scalar loads).
    float zs[4], vs[4], qsx[4];
#pragma unroll
    for (int i = 0; i < 4; ++i) {
        zs[i]  = Z0[wid0 + i];
        vs[i]  = V0[wid0 + i];
        qsx[i] = q0[wid0 + i];
    }

    vf4 buf[2][8];                             // double-buffered raw loads
#pragma unroll
    for (int j = 0; j < 8; ++j)
        buf[0][j] = *(const vf4*)(x + (size_t)wid0 * TLEN + j * 256 + lane * 4);

#pragma unroll
    for (int i = 0; i < 4; ++i) {              // fully unrolled: static idx
        const int wid = wid0 + i;

        // ---- prefetch next series (flies under this series' scan) ----
        if (i < 3) {
#pragma unroll
            for (int j = 0; j < 8; ++j)
                buf[(i + 1) & 1][j] =
                    *(const vf4*)(x + (size_t)(wid + 1) * TLEN + j * 256 + lane * 4);
        }

        // ---- transpose-in (waits only this series' loads) ----
#pragma unroll
        for (int j = 0; j < 8; ++j)
            *(vf4*)(W + j * 256 + goff) = buf[i & 1][j];
        vf4 xv[8];
#pragma unroll
        for (int m = 0; m < 8; ++m)
            xv[m] = *(const vf4*)(W + lbase + ((m ^ l7) << 2));

        // ---- fold: compose 32 per-step affine maps (p == az) ----
        float az = 1.f, bz = 0.f, r = 0.f, s = 0.f, f = 1.f, g = 0.f;
#pragma unroll
        for (int m = 0; m < 8; ++m) {
#pragma unroll
            for (int k = 0; k < 4; ++k) {
                const float xt = xv[m][k];
                const bool  nz = (xt != 0.f);
                const float az_n = ma * az;
                const float bz_n = fmaf(ma, bz, a * xt);
                const float r_n  = fmaf(ma, r, a * f);
                const float s_n  = fmaf(ma, s, a * g);
                az = nz ? az_n : az;
                bz = nz ? bz_n : bz;
                r  = nz ? r_n  : r;
                s  = nz ? s_n  : s;
                g  = nz ? 1.f  : (g + 1.f);   // r_n,s_n already took old f,g
                f  = nz ? 0.f  : f;
            }
        }

        // ---- inclusive Hillis-Steele compose scan across 64 lanes ----
#pragma unroll
        for (int d = 1; d < 64; d <<= 1) {
            const float az_o = __shfl_up(az, d);
            const float bz_o = __shfl_up(bz, d);
            const float r_o  = __shfl_up(r,  d);
            const float s_o  = __shfl_up(s,  d);
            const float f_o  = __shfl_up(f,  d);
            const float g_o  = __shfl_up(g,  d);
            if (lane >= d) {
                bz = fmaf(az, bz_o, bz);
                s  = fmaf(az, s_o, fmaf(r, g_o, s));
                r  = fmaf(az, r_o, r * f_o);
                az = az * az_o;
                g  = fmaf(f, g_o, g);
                f  = f * f_o;
            }
        }

        // ---- exclusive prefix (shift one lane; identity at lane 0) ----
        float azE = __shfl_up(az, 1), bzE = __shfl_up(bz, 1);
        float rE  = __shfl_up(r, 1),  sE  = __shfl_up(s, 1);
        float fE  = __shfl_up(f, 1),  gE  = __shfl_up(g, 1);
        if (lane == 0) {
            azE = 1.f; bzE = 0.f; rE = 0.f; sE = 0.f; fE = 1.f; gE = 0.f;
        }

        // ---- state at this lane's window start (exact) ----
        float Z = fmaf(azE, zs[i], bzE);
        float V = fmaf(azE, vs[i], fmaf(rE, qsx[i], sE));
        float q = fmaf(fE, qsx[i], gE);

        // ---- replay 32 steps, emit out = Z'/V' ----
#pragma unroll
        for (int m = 0; m < 8; ++m) {
#pragma unroll
            for (int k = 0; k < 4; ++k) {
                const float xt = xv[m][k];
                const bool  nz = (xt != 0.f);
                const float Zn = fmaf(ma, Z, a * xt);
                const float Vn = fmaf(ma, V, a * q);
                Z = nz ? Zn : Z;
                V = nz ? Vn : V;
                q = nz ? 1.f : (q + 1.f);
                xv[m][k] = Z * __builtin_amdgcn_rcpf(V);
            }
        }

        // ---- transpose-out -> coalesced stores (drain under next scan) ----
#pragma unroll
        for (int m = 0; m < 8; ++m)
            *(vf4*)(W + lbase + ((m ^ l7) << 2)) = xv[m];
#pragma unroll
        for (int j = 0; j < 8; ++j) {
            const vf4 o = *(const vf4*)(W + j * 256 + goff);
            *(vf4*)(out + (size_t)wid * TLEN + j * 256 + lane * 4) = o;
        }
    }
}

extern "C" void kernel_launch(void* const* d_in, const int* in_sizes, int n_in,
                              void* d_out, int out_size, void* d_ws, size_t ws_size,
                              hipStream_t stream) {
    const float* x     = (const float*)d_in[0];
    const float* alpha = (const float*)d_in[1];
    const float* Z0    = (const float*)d_in[2];
    const float* V0    = (const float*)d_in[3];
    const float* q0    = (const float*)d_in[4];
    float* out = (float*)d_out;

    // 2048 waves x 4 consecutive series each; 512 blocks = 2 blocks/CU
    // (32KB LDS each), 8 waves/CU in a cross-series software pipeline.
    dim3 block(256);
    dim3 grid(512);
    croston_kernel<<<grid, block, 0, stream>>>(x, alpha, Z0, V0, q0, out);
}